// Round 6
// baseline (373.364 us; speedup 1.0000x reference)
//
#include <hip/hip_runtime.h>
#include <math.h>

// ---------------------------------------------------------------------------
// AttentionNet round 6: 32x32x64 scaled MFMA (half the MFMA instruction count
// of round 5's 16x16x128; same FLOPs, same LDS traffic) + rsum memsets folded
// into convert_w8 (2 fewer dispatches). Everything else = round 5:
// fused softmax-into-GEMM (no-max-sub, rsum atomics), MX-fp8 e4m3 unit-scale,
// 128x128 tiles, XOR-swizzled LDS (0 conflicts), fused epilogues, 11 dispatches.
// C/D layout 32x32: col=lane&31, row=(reg&3)+8*(reg>>2)+4*(lane>>5)  [m74/m101]
// Scales (pow2, folded into alphas): x*8, W*256, L1 QKV*8, L2 QKV*1024,
// P = expS*2^-4, Hs1*256, Hs2*65536, h2*256.
// ---------------------------------------------------------------------------

typedef __attribute__((ext_vector_type(8))) int i32x8;
typedef __attribute__((ext_vector_type(4))) int i32x4;
typedef __attribute__((ext_vector_type(16))) float f32x16;
typedef unsigned char u8;
typedef unsigned int u32;

#define EPI_F32 0
#define EPI_F8 1
#define EPI_QKV 2
#define EPI_EXP 3
#define EPI_PV 4

__device__ __forceinline__ void gload_lds16(const void* g, void* l) {
    __builtin_amdgcn_global_load_lds(
        (const __attribute__((address_space(1))) void*)g,
        (__attribute__((address_space(3))) void*)l, 16, 0, 0);
}

__device__ __forceinline__ u8 cvt_f8(float v) {
    return (u8)(__builtin_amdgcn_cvt_pk_fp8_f32(v, v, 0, false) & 0xFF);
}

// C = epilogue(alpha * (A @ B^T)); A=[M,K] fp8, B=[N,K] fp8, batch=blockIdx.z.
// K % 128 == 0; ld*/bs* in fp8 elements (= bytes) for fp8 tensors.
template <int EPI>
__global__ __launch_bounds__(256) void gemm_fp8(
    const u8* __restrict__ A, const u8* __restrict__ B,
    void* __restrict__ C0, void* __restrict__ C1, void* __restrict__ C2,
    int K, int ldA, int ldB, int ldC,
    long long bsA, long long bsB, long long bsC, float alpha, float beta)
{
    __shared__ u8 sA[128 * 128];
    __shared__ u8 sB[128 * 128];

    const int tid = threadIdx.x;
    const int wave = tid >> 6, lane = tid & 63;
    const int wm = wave >> 1, wn = wave & 1;
    const int m0 = blockIdx.y * 128, n0 = blockIdx.x * 128;
    const long long z = blockIdx.z;

    const u8* pA = A + z * bsA;
    const u8* pB = B + z * bsB;

    // Staging: tile = 128 rows x 8 16B-chunks; LDS chunk (row,c) holds global
    // chunk c ^ (row&7). global_load_lds dst = wave-uniform base + lane*16.
    int blkid[4], rs_[4], cs16[4];
#pragma unroll
    for (int i = 0; i < 4; i++) {
        blkid[i] = wave * 256 + i * 64 + lane;
        rs_[i] = blkid[i] >> 3;
        cs16[i] = ((blkid[i] & 7) ^ (rs_[i] & 7)) * 16;
    }

    f32x16 acc[2][2] = {};
    const int l31 = lane & 31;
    const int lh = lane >> 5;        // 0/1: k-half selector within frag
    const int half4 = lh * 4;        // C/D row offset

    for (int k0 = 0; k0 < K; k0 += 128) {
#pragma unroll
        for (int i = 0; i < 4; i++) {
            gload_lds16(pA + (long long)(m0 + rs_[i]) * ldA + k0 + cs16[i],
                        sA + blkid[i] * 16);
            gload_lds16(pB + (long long)(n0 + rs_[i]) * ldB + k0 + cs16[i],
                        sB + blkid[i] * 16);
        }
        __syncthreads();

#pragma unroll
        for (int h = 0; h < 2; h++) {
            const int c0 = h * 4 + lh * 2;
            i32x8 a[2], b[2];
#pragma unroll
            for (int i = 0; i < 2; i++) {
                const int row = wm * 64 + i * 32 + l31;
                const int sw = row & 7;
                i32x4 lo = *(const i32x4*)(sA + row * 128 + ((c0 + 0) ^ sw) * 16);
                i32x4 hi = *(const i32x4*)(sA + row * 128 + ((c0 + 1) ^ sw) * 16);
                a[i] = __builtin_shufflevector(lo, hi, 0, 1, 2, 3, 4, 5, 6, 7);
            }
#pragma unroll
            for (int j = 0; j < 2; j++) {
                const int row = wn * 64 + j * 32 + l31;
                const int sw = row & 7;
                i32x4 lo = *(const i32x4*)(sB + row * 128 + ((c0 + 0) ^ sw) * 16);
                i32x4 hi = *(const i32x4*)(sB + row * 128 + ((c0 + 1) ^ sw) * 16);
                b[j] = __builtin_shufflevector(lo, hi, 0, 1, 2, 3, 4, 5, 6, 7);
            }
#pragma unroll
            for (int i = 0; i < 2; i++)
#pragma unroll
                for (int j = 0; j < 2; j++)
                    acc[i][j] = __builtin_amdgcn_mfma_scale_f32_32x32x64_f8f6f4(
                        a[i], b[j], acc[i][j], 0 /*A=e4m3*/, 0 /*B=e4m3*/,
                        0, 0x7F7F7F7F, 0, 0x7F7F7F7F);
        }
        __syncthreads();
    }

    // C/D: col = lane&31, row = (reg&3) + 8*(reg>>2) + 4*(lane>>5)
    const int col = l31;

    if (EPI == EPI_EXP) {
        u8* P = (u8*)C0 + z * bsC;
        float* rsum = (float*)C1 + z * 2048;
#pragma unroll
        for (int i = 0; i < 2; i++) {
            const int mbase = m0 + wm * 64 + i * 32;
            float rowp[16];
#pragma unroll
            for (int g = 0; g < 16; g++) rowp[g] = 0.f;
#pragma unroll
            for (int j = 0; j < 2; j++) {
                const int nloc = n0 + wn * 64 + j * 32 + col;
#pragma unroll
                for (int g = 0; g < 16; g++) {
                    const int mloc = mbase + (g & 3) + 8 * (g >> 2) + half4;
                    float e = __expf(acc[i][j][g] * alpha);
                    rowp[g] += e;
                    P[(long long)mloc * ldC + nloc] = cvt_f8(e * 0.0625f);
                }
            }
#pragma unroll
            for (int g = 0; g < 16; g++) {
                float t = rowp[g];
                t += __shfl_xor(t, 1);
                t += __shfl_xor(t, 2);
                t += __shfl_xor(t, 4);
                t += __shfl_xor(t, 8);
                t += __shfl_xor(t, 16);
                if (col == 0) {
                    const int mloc = mbase + (g & 3) + 8 * (g >> 2) + half4;
                    atomicAdd(&rsum[mloc], t);
                }
            }
        }
        return;
    }

#pragma unroll
    for (int i = 0; i < 2; i++) {
        const int mbase = m0 + wm * 64 + i * 32;
        float inv[16];
        if (EPI == EPI_PV) {
            const float* rsum = (const float*)C1 + z * 2048;
#pragma unroll
            for (int g = 0; g < 16; g++)
                inv[g] = alpha / rsum[mbase + (g & 3) + 8 * (g >> 2) + half4];
        }
#pragma unroll
        for (int j = 0; j < 2; j++) {
            const int nloc = n0 + wn * 64 + j * 32 + col;
            if (EPI == EPI_F32) {
                float* C = (float*)C0 + z * bsC;
#pragma unroll
                for (int g = 0; g < 16; g++) {
                    const int mloc = mbase + (g & 3) + 8 * (g >> 2) + half4;
                    C[(long long)mloc * ldC + nloc] = acc[i][j][g] * alpha;
                }
            } else if (EPI == EPI_F8) {
                u8* C = (u8*)C0 + z * bsC;
#pragma unroll
                for (int g = 0; g < 16; g++) {
                    const int mloc = mbase + (g & 3) + 8 * (g >> 2) + half4;
                    C[(long long)mloc * ldC + nloc] = cvt_f8(acc[i][j][g] * alpha);
                }
            } else if (EPI == EPI_PV) {
                u8* C = (u8*)C0 + z * bsC;
#pragma unroll
                for (int g = 0; g < 16; g++) {
                    const int mloc = mbase + (g & 3) + 8 * (g >> 2) + half4;
                    float v = acc[i][j][g] * inv[g];
                    v = v / (1.f + __expf(-v));   // silu
                    C[(long long)mloc * ldC + nloc] = cvt_f8(v * beta);
                }
            } else { // EPI_QKV: n-segment 0->Q, 1->K, 2->V^T (S=2048,D=1024)
                const int seg = nloc >> 10;
                const int nn = nloc & 1023;
                if (seg == 2) {
                    // pack 4 consecutive m per reg-group into one u32 store
#pragma unroll
                    for (int g = 0; g < 4; g++) {
                        const int mloc = mbase + 8 * g + half4;
                        const int bb = mloc >> 11, mm = mloc & 2047;
                        float v0 = acc[i][j][4 * g + 0] * alpha;
                        float v1 = acc[i][j][4 * g + 1] * alpha;
                        float v2 = acc[i][j][4 * g + 2] * alpha;
                        float v3 = acc[i][j][4 * g + 3] * alpha;
                        int p01 = __builtin_amdgcn_cvt_pk_fp8_f32(v0, v1, 0, false);
                        int p23 = __builtin_amdgcn_cvt_pk_fp8_f32(v2, v3, 0, false);
                        u32 pk = (u32)(p01 & 0xFFFF) | ((u32)p23 << 16);
                        *(u32*)((u8*)C2 + (long long)bb * (1024LL * 2048) +
                                (long long)nn * 2048 + mm) = pk;
                    }
                } else {
                    u8* C = seg ? (u8*)C1 : (u8*)C0;
#pragma unroll
                    for (int g = 0; g < 16; g++) {
                        const int mloc = mbase + (g & 3) + 8 * (g >> 2) + half4;
                        C[(long long)mloc * 1024 + nn] =
                            cvt_f8(acc[i][j][g] * alpha);
                    }
                }
            }
        }
    }
}

// fp32 -> fp8 with scale; n % 1024 == 0
__global__ __launch_bounds__(256) void convert_fp8(
    const float* __restrict__ in, u8* __restrict__ o, long long n, float scale)
{
    long long i = ((long long)blockIdx.x * 256 + threadIdx.x) * 4;
    if (i >= n) return;
    float4 v = *(const float4*)(in + i);
    int p01 = __builtin_amdgcn_cvt_pk_fp8_f32(v.x * scale, v.y * scale, 0, false);
    int p23 = __builtin_amdgcn_cvt_pk_fp8_f32(v.z * scale, v.w * scale, 0, false);
    *(u32*)(o + i) = (u32)(p01 & 0xFFFF) | ((u32)p23 << 16);
}

// all 8 weights (1024x1024 each) -> fp8 * 256; also zeros rz[16384] floats
// (the two per-layer rsum buffers) from the first 16 blocks of row y==0.
__global__ __launch_bounds__(256) void convert_w8(
    const float* w0, const float* w1, const float* w2, const float* w3,
    const float* w4, const float* w5, const float* w6, const float* w7,
    u8* __restrict__ o, float* __restrict__ rz)
{
    if (blockIdx.y == 0 && blockIdx.x < 16) {
        float4 zero = {0.f, 0.f, 0.f, 0.f};
        *(float4*)(rz + ((long long)blockIdx.x * 256 + threadIdx.x) * 4) = zero;
    }
    const float* ws[8] = {w0, w1, w2, w3, w4, w5, w6, w7};
    const float* src = ws[blockIdx.y];
    long long i = ((long long)blockIdx.x * 256 + threadIdx.x) * 4;
    float4 v = *(const float4*)(src + i);
    int p01 = __builtin_amdgcn_cvt_pk_fp8_f32(v.x * 256.f, v.y * 256.f, 0, false);
    int p23 = __builtin_amdgcn_cvt_pk_fp8_f32(v.z * 256.f, v.w * 256.f, 0, false);
    *(u32*)(o + (long long)blockIdx.y * 1024 * 1024 + i) =
        (u32)(p01 & 0xFFFF) | ((u32)p23 << 16);
}

// Row softmax over 1024 fp32 -> fp32 out
__global__ __launch_bounds__(256) void softmax_1024(
    const float* __restrict__ in, float* __restrict__ out)
{
    const float* p = in + (long long)blockIdx.x * 1024;
    float* o = out + (long long)blockIdx.x * 1024;
    const int tid = threadIdx.x;
    const int lane = tid & 63, wv = tid >> 6;
    __shared__ float redm[4], reds[4];

    float4 v = *(const float4*)(p + tid * 4);
    float vals[4] = {v.x, v.y, v.z, v.w};

    float m = -INFINITY;
#pragma unroll
    for (int i = 0; i < 4; i++) m = fmaxf(m, vals[i]);
#pragma unroll
    for (int off = 32; off; off >>= 1) m = fmaxf(m, __shfl_xor(m, off));
    if (lane == 0) redm[wv] = m;
    __syncthreads();
    m = fmaxf(fmaxf(redm[0], redm[1]), fmaxf(redm[2], redm[3]));

    float s = 0.f;
#pragma unroll
    for (int i = 0; i < 4; i++) {
        vals[i] = __expf(vals[i] - m);
        s += vals[i];
    }
#pragma unroll
    for (int off = 32; off; off >>= 1) s += __shfl_xor(s, off);
    if (lane == 0) reds[wv] = s;
    __syncthreads();
    s = reds[0] + reds[1] + reds[2] + reds[3];
    const float inv = 1.0f / s;
    float4 ov;
    ov.x = vals[0] * inv; ov.y = vals[1] * inv;
    ov.z = vals[2] * inv; ov.w = vals[3] * inv;
    *(float4*)(o + tid * 4) = ov;
}

extern "C" void kernel_launch(void* const* d_in, const int* in_sizes, int n_in,
                              void* d_out, int out_size, void* d_ws, size_t ws_size,
                              hipStream_t stream)
{
    const float* x = (const float*)d_in[0];
    float* out = (float*)d_out;

    constexpr int Bt = 4, S = 2048, D = 1024;
    constexpr int M = Bt * S;                  // 8192
    const long long MD = (long long)M * D;     // 8,388,608
    const long long DD = (long long)D * D;
    const long long SD = (long long)S * D;
    const long long SS = (long long)S * S;

    // ws layout: Af 8MB | Wf 8MB | Qf 8 | Kf 8 | VT 8 | Pf 16MB | Hs 8MB |
    // SC fp32 32MB | rsum0/rsum1 64KB   => ~96 MB
    u8* Af = (u8*)d_ws;
    u8* Wf = Af + MD;
    u8* Qf = Wf + 8 * DD;
    u8* Kf = Qf + MD;
    u8* VT = Kf + MD;
    u8* Pf = VT + MD;
    u8* Hs = Pf + (long long)Bt * SS;
    float* SC = (float*)(Hs + MD);
    float* rsum0 = SC + MD;
    float* rsum1 = rsum0 + M;

    const dim3 blk(256);

    // per-layer alphas (exact pow2 folds; see header comment)
    const float SOFT = 0.08838834764831845f; // 1/sqrt(128)
    const float a_qkv[2] = {8.f / 2048.f, 1024.f / 65536.f};
    const float a_qk[2]  = {SOFT / 64.f, SOFT / 1048576.f};
    const float a_pv[2]  = {2.0f, 1.f / 64.f};        // then / rsum
    const float b_pv[2]  = {256.f, 65536.f};          // Hs store scale
    const float a_fc[2]  = {256.f / 65536.f, 1.f / 16777216.f};

    convert_fp8<<<dim3((int)(MD / 1024)), blk, 0, stream>>>(x, Af, MD, 8.f);
    convert_w8<<<dim3((int)(DD / 1024), 8), blk, 0, stream>>>(
        (const float*)d_in[1], (const float*)d_in[2], (const float*)d_in[3],
        (const float*)d_in[4], (const float*)d_in[5], (const float*)d_in[6],
        (const float*)d_in[7], (const float*)d_in[8], Wf, rsum0);

    const dim3 gqkv(3 * D / 128, M / 128, 1);  // fused QKV projection
    const dim3 gw(D / 128, M / 128, 1);        // fc GEMMs
    const dim3 gqk(S / 128, S / 128, Bt);      // QK^T per batch
    const dim3 gpv(D / 128, S / 128, Bt);      // P @ V (B = V^T) per batch

    for (int layer = 0; layer < 2; layer++) {
        const u8* wqkv = Wf + (long long)(layer * 4) * DD; // wq|wk|wv contiguous
        const u8* fc   = Wf + (long long)(layer * 4 + 3) * DD;
        float* rsum    = layer ? rsum1 : rsum0;

        gemm_fp8<EPI_QKV><<<gqkv, blk, 0, stream>>>(
            Af, wqkv, Qf, Kf, VT, D, D, D, D, 0, 0, 0, a_qkv[layer], 0.f);
        // P = fp8(exp(score)/16), rsum = sum(exp(score)) per row
        gemm_fp8<EPI_EXP><<<gqk, blk, 0, stream>>>(
            Qf, Kf, Pf, rsum, nullptr, D, D, D, S, SD, SD, SS,
            a_qk[layer], 0.f);
        // Hs = fp8(silu(P@V / rsum) * b_pv)
        gemm_fp8<EPI_PV><<<gpv, blk, 0, stream>>>(
            Pf, VT, Hs, rsum, nullptr, S, S, S, D, SS, (long long)D * S, SD,
            a_pv[layer], b_pv[layer]);
        if (layer == 0) {
            gemm_fp8<EPI_F8><<<gw, blk, 0, stream>>>(
                Hs, fc, Af, nullptr, nullptr, D, D, D, D, 0, 0, 0,
                a_fc[0], 0.f);
        } else {
            gemm_fp8<EPI_F32><<<gw, blk, 0, stream>>>(
                Hs, fc, SC, nullptr, nullptr, D, D, D, D, 0, 0, 0,
                a_fc[1], 0.f);
        }
    }

    softmax_1024<<<dim3(M), blk, 0, stream>>>(SC, out);
}

// Round 7
// 352.835 us; speedup vs baseline: 1.0582x; 1.0582x over previous
//
#include <hip/hip_runtime.h>
#include <math.h>

// ---------------------------------------------------------------------------
// AttentionNet round 7: revert to round-5 16x16x128 MFMA core (round 6's
// 32x32x64 caused 4-way LDS bank conflicts: row stride 128B == 0 mod bank
// period, so rows r,r+8,r+16,r+24 alias; 16x16 only aliases 2-way = free).
// New vs r5: single fused convert dispatch (x + 8 weights + rsum zeroing),
// fc2 epilogue computes exp(logit) + row-sum atomics (no-max-sub; logits
// |x|<~1e-3), final kernel is a pure normalize. 10 dispatches total.
// Scales (pow2, folded into alphas): x*8, W*256, L1 QKV*8, L2 QKV*1024,
// P = expS*2^-4, Hs1*256, Hs2*65536, h2*256.
// ---------------------------------------------------------------------------

typedef __attribute__((ext_vector_type(8))) int i32x8;
typedef __attribute__((ext_vector_type(4))) int i32x4;
typedef __attribute__((ext_vector_type(4))) float f32x4;
typedef unsigned char u8;
typedef unsigned int u32;

#define EPI_F8 1
#define EPI_QKV 2
#define EPI_EXP 3
#define EPI_PV 4
#define EPI_EXPF32 5

__device__ __forceinline__ void gload_lds16(const void* g, void* l) {
    __builtin_amdgcn_global_load_lds(
        (const __attribute__((address_space(1))) void*)g,
        (__attribute__((address_space(3))) void*)l, 16, 0, 0);
}

__device__ __forceinline__ u8 cvt_f8(float v) {
    return (u8)(__builtin_amdgcn_cvt_pk_fp8_f32(v, v, 0, false) & 0xFF);
}

// C = epilogue(alpha * (A @ B^T)); A=[M,K] fp8, B=[N,K] fp8, batch=blockIdx.z.
// K % 128 == 0; ld*/bs* in fp8 elements (= bytes) for fp8 tensors.
template <int EPI>
__global__ __launch_bounds__(256) void gemm_fp8(
    const u8* __restrict__ A, const u8* __restrict__ B,
    void* __restrict__ C0, void* __restrict__ C1, void* __restrict__ C2,
    int K, int ldA, int ldB, int ldC,
    long long bsA, long long bsB, long long bsC, float alpha, float beta)
{
    __shared__ u8 sA[128 * 128];
    __shared__ u8 sB[128 * 128];

    const int tid = threadIdx.x;
    const int wave = tid >> 6, lane = tid & 63;
    const int wm = wave >> 1, wn = wave & 1;
    const int m0 = blockIdx.y * 128, n0 = blockIdx.x * 128;
    const long long z = blockIdx.z;

    const u8* pA = A + z * bsA;
    const u8* pB = B + z * bsB;

    // Tile = 128 rows x 8 16B-chunks. LDS chunk (row,c) holds global chunk
    // c ^ (row&7). global_load_lds dst must be wave-uniform base + lane*16.
    int blkid[4], rs_[4], cs16[4];
#pragma unroll
    for (int i = 0; i < 4; i++) {
        blkid[i] = wave * 256 + i * 64 + lane;
        rs_[i] = blkid[i] >> 3;
        cs16[i] = ((blkid[i] & 7) ^ (rs_[i] & 7)) * 16;
    }

    f32x4 acc[4][4] = {};
    const int fr = lane & 15, fc2 = (lane >> 4) * 2;

    for (int k0 = 0; k0 < K; k0 += 128) {
#pragma unroll
        for (int i = 0; i < 4; i++) {
            gload_lds16(pA + (long long)(m0 + rs_[i]) * ldA + k0 + cs16[i],
                        sA + blkid[i] * 16);
            gload_lds16(pB + (long long)(n0 + rs_[i]) * ldB + k0 + cs16[i],
                        sB + blkid[i] * 16);
        }
        __syncthreads();

        i32x8 a[4], b[4];
#pragma unroll
        for (int i = 0; i < 4; i++) {
            const int row = wm * 64 + i * 16 + fr;
            const int sw = row & 7;
            i32x4 lo = *(const i32x4*)(sA + row * 128 + ((fc2 + 0) ^ sw) * 16);
            i32x4 hi = *(const i32x4*)(sA + row * 128 + ((fc2 + 1) ^ sw) * 16);
            a[i] = __builtin_shufflevector(lo, hi, 0, 1, 2, 3, 4, 5, 6, 7);
        }
#pragma unroll
        for (int j = 0; j < 4; j++) {
            const int row = wn * 64 + j * 16 + fr;
            const int sw = row & 7;
            i32x4 lo = *(const i32x4*)(sB + row * 128 + ((fc2 + 0) ^ sw) * 16);
            i32x4 hi = *(const i32x4*)(sB + row * 128 + ((fc2 + 1) ^ sw) * 16);
            b[j] = __builtin_shufflevector(lo, hi, 0, 1, 2, 3, 4, 5, 6, 7);
        }
#pragma unroll
        for (int i = 0; i < 4; i++)
#pragma unroll
            for (int j = 0; j < 4; j++)
                acc[i][j] = __builtin_amdgcn_mfma_scale_f32_16x16x128_f8f6f4(
                    a[i], b[j], acc[i][j], 0 /*A=e4m3*/, 0 /*B=e4m3*/,
                    0, 0x7F7F7F7F, 0, 0x7F7F7F7F);
        __syncthreads();
    }

    // C/D layout: col = lane&15, row = (lane>>4)*4 + reg
    const int col = lane & 15;
    const int rbase = (lane >> 4) * 4;

    if (EPI == EPI_EXP || EPI == EPI_EXPF32) {
        // EXP:    P[z][m][n] = fp8(exp(acc*alpha)*2^-4), rsum[z*2048+m] += e
        // EXPF32: C[m][n]    = exp(acc*alpha) (fp32),    rsum[m] += e
        u8* P = (u8*)C0 + z * bsC;
        float* Cw = (float*)C0 + z * bsC;
        float* rsum = (EPI == EPI_EXP) ? ((float*)C1 + z * 2048) : (float*)C1;
#pragma unroll
        for (int i = 0; i < 4; i++) {
            const int mloc0 = m0 + wm * 64 + i * 16 + rbase;
            float rowp[4] = {0.f, 0.f, 0.f, 0.f};
#pragma unroll
            for (int j = 0; j < 4; j++) {
                const int nloc = n0 + wn * 64 + j * 16 + col;
#pragma unroll
                for (int r = 0; r < 4; r++) {
                    float e = __expf(acc[i][j][r] * alpha);
                    rowp[r] += e;
                    if (EPI == EPI_EXP)
                        P[(long long)(mloc0 + r) * ldC + nloc] =
                            cvt_f8(e * 0.0625f);
                    else
                        Cw[(long long)(mloc0 + r) * ldC + nloc] = e;
                }
            }
#pragma unroll
            for (int r = 0; r < 4; r++) {
                float t = rowp[r];
                t += __shfl_xor(t, 1);
                t += __shfl_xor(t, 2);
                t += __shfl_xor(t, 4);
                t += __shfl_xor(t, 8);
                if ((lane & 15) == 0) atomicAdd(&rsum[mloc0 + r], t);
            }
        }
        return;
    }

#pragma unroll
    for (int i = 0; i < 4; i++) {
        const int mloc0 = m0 + wm * 64 + i * 16 + rbase;
        float inv[4];
        if (EPI == EPI_PV) {
            const float* rsum = (const float*)C1 + z * 2048;
#pragma unroll
            for (int r = 0; r < 4; r++) inv[r] = alpha / rsum[mloc0 + r];
        }
#pragma unroll
        for (int j = 0; j < 4; j++) {
            const int nloc = n0 + wn * 64 + j * 16 + col;
            if (EPI == EPI_F8) {
                u8* C = (u8*)C0 + z * bsC;
#pragma unroll
                for (int r = 0; r < 4; r++)
                    C[(long long)(mloc0 + r) * ldC + nloc] =
                        cvt_f8(acc[i][j][r] * alpha);
            } else if (EPI == EPI_PV) {
                u8* C = (u8*)C0 + z * bsC;
#pragma unroll
                for (int r = 0; r < 4; r++) {
                    float v = acc[i][j][r] * inv[r];
                    v = v / (1.f + __expf(-v));   // silu
                    C[(long long)(mloc0 + r) * ldC + nloc] = cvt_f8(v * beta);
                }
            } else { // EPI_QKV: n-segment 0->Q, 1->K, 2->V^T (S=2048,D=1024)
                const int seg = nloc >> 10;
                const int nn = nloc & 1023;
                float v[4];
#pragma unroll
                for (int r = 0; r < 4; r++) v[r] = acc[i][j][r] * alpha;
                if (seg == 2) {
                    const int bb = mloc0 >> 11, mm = mloc0 & 2047;
                    int p01 = __builtin_amdgcn_cvt_pk_fp8_f32(v[0], v[1], 0, false);
                    int p23 = __builtin_amdgcn_cvt_pk_fp8_f32(v[2], v[3], 0, false);
                    u32 pk = (u32)(p01 & 0xFFFF) | ((u32)p23 << 16);
                    *(u32*)((u8*)C2 + (long long)bb * (1024LL * 2048) +
                            (long long)nn * 2048 + mm) = pk;
                } else {
                    u8* C = seg ? (u8*)C1 : (u8*)C0;
#pragma unroll
                    for (int r = 0; r < 4; r++)
                        C[(long long)(mloc0 + r) * 1024 + nn] = cvt_f8(v[r]);
                }
            }
        }
    }
}

// One dispatch: x (8192 blocks, scale 8) + 8 weights (8192 blocks, scale 256)
// -> fp8; blocks 0..23 also zero the 3 rsum buffers (24576 floats at rz).
__global__ __launch_bounds__(256) void convert_all(
    const float* x, const float* w0, const float* w1, const float* w2,
    const float* w3, const float* w4, const float* w5, const float* w6,
    const float* w7, u8* __restrict__ ax, u8* __restrict__ wf,
    float* __restrict__ rz)
{
    const int bid = blockIdx.x;
    if (bid < 24) {
        float4 zero = {0.f, 0.f, 0.f, 0.f};
        *(float4*)(rz + ((long long)bid * 256 + threadIdx.x) * 4) = zero;
    }
    const float* src;
    u8* dst;
    float scale;
    long long i;
    if (bid < 8192) {
        src = x; dst = ax; scale = 8.f;
        i = ((long long)bid * 256 + threadIdx.x) * 4;
    } else {
        const float* ws[8] = {w0, w1, w2, w3, w4, w5, w6, w7};
        const int wi = (bid - 8192) >> 10;
        src = ws[wi]; scale = 256.f;
        dst = wf + (long long)wi * 1024 * 1024;
        i = (((long long)(bid - 8192) & 1023) * 256 + threadIdx.x) * 4;
    }
    float4 v = *(const float4*)(src + i);
    int p01 = __builtin_amdgcn_cvt_pk_fp8_f32(v.x * scale, v.y * scale, 0, false);
    int p23 = __builtin_amdgcn_cvt_pk_fp8_f32(v.z * scale, v.w * scale, 0, false);
    *(u32*)(dst + i) = (u32)(p01 & 0xFFFF) | ((u32)p23 << 16);
}

// out[row][c] = e[row][c] / rsum[row]  (1024 cols, fp32)
__global__ __launch_bounds__(256) void normalize_1024(
    const float* __restrict__ e, const float* __restrict__ rsum,
    float* __restrict__ out)
{
    const long long row = blockIdx.x;
    const float inv = 1.0f / rsum[row];
    const float* p = e + row * 1024;
    float* o = out + row * 1024;
    float4 v = *(const float4*)(p + threadIdx.x * 4);
    float4 ov;
    ov.x = v.x * inv; ov.y = v.y * inv; ov.z = v.z * inv; ov.w = v.w * inv;
    *(float4*)(o + threadIdx.x * 4) = ov;
}

extern "C" void kernel_launch(void* const* d_in, const int* in_sizes, int n_in,
                              void* d_out, int out_size, void* d_ws, size_t ws_size,
                              hipStream_t stream)
{
    float* out = (float*)d_out;

    constexpr int Bt = 4, S = 2048, D = 1024;
    constexpr int M = Bt * S;                  // 8192
    const long long MD = (long long)M * D;     // 8,388,608
    const long long DD = (long long)D * D;
    const long long SD = (long long)S * D;
    const long long SS = (long long)S * S;

    // ws layout: Af 8MB | Wf 8MB | Qf 8 | Kf 8 | VT 8 | Pf 16MB | Hs 8MB |
    // SC fp32 32MB | rsum0|rsum1|rsum2 (3 x 32KB)   => ~96 MB
    u8* Af = (u8*)d_ws;
    u8* Wf = Af + MD;
    u8* Qf = Wf + 8 * DD;
    u8* Kf = Qf + MD;
    u8* VT = Kf + MD;
    u8* Pf = VT + MD;
    u8* Hs = Pf + (long long)Bt * SS;
    float* SC = (float*)(Hs + MD);
    float* rsum0 = SC + MD;
    float* rsum1 = rsum0 + M;
    float* rsum2 = rsum1 + M;

    const dim3 blk(256);

    // per-layer alphas (exact pow2 folds; see header comment)
    const float SOFT = 0.08838834764831845f; // 1/sqrt(128)
    const float a_qkv[2] = {8.f / 2048.f, 1024.f / 65536.f};
    const float a_qk[2]  = {SOFT / 64.f, SOFT / 1048576.f};
    const float a_pv[2]  = {2.0f, 1.f / 64.f};        // then / rsum
    const float b_pv[2]  = {256.f, 65536.f};          // Hs store scale
    const float a_fc[2]  = {256.f / 65536.f, 1.f / 16777216.f};

    convert_all<<<dim3(16384), blk, 0, stream>>>(
        (const float*)d_in[0], (const float*)d_in[1], (const float*)d_in[2],
        (const float*)d_in[3], (const float*)d_in[4], (const float*)d_in[5],
        (const float*)d_in[6], (const float*)d_in[7], (const float*)d_in[8],
        Af, Wf, rsum0);

    const dim3 gqkv(3 * D / 128, M / 128, 1);  // fused QKV projection
    const dim3 gw(D / 128, M / 128, 1);        // fc GEMMs
    const dim3 gqk(S / 128, S / 128, Bt);      // QK^T per batch
    const dim3 gpv(D / 128, S / 128, Bt);      // P @ V (B = V^T) per batch

    for (int layer = 0; layer < 2; layer++) {
        const u8* wqkv = Wf + (long long)(layer * 4) * DD; // wq|wk|wv contiguous
        const u8* fc   = Wf + (long long)(layer * 4 + 3) * DD;
        float* rsum    = layer ? rsum1 : rsum0;

        gemm_fp8<EPI_QKV><<<gqkv, blk, 0, stream>>>(
            Af, wqkv, Qf, Kf, VT, D, D, D, D, 0, 0, 0, a_qkv[layer], 0.f);
        // P = fp8(exp(score)/16), rsum = sum(exp(score)) per row
        gemm_fp8<EPI_EXP><<<gqk, blk, 0, stream>>>(
            Qf, Kf, Pf, rsum, nullptr, D, D, D, S, SD, SD, SS,
            a_qk[layer], 0.f);
        // Hs = fp8(silu(P@V / rsum) * b_pv)
        gemm_fp8<EPI_PV><<<gpv, blk, 0, stream>>>(
            Pf, VT, Hs, rsum, nullptr, S, S, S, D, SS, (long long)D * S, SD,
            a_pv[layer], b_pv[layer]);
        if (layer == 0) {
            gemm_fp8<EPI_F8><<<gw, blk, 0, stream>>>(
                Hs, fc, Af, nullptr, nullptr, D, D, D, D, 0, 0, 0,
                a_fc[0], 0.f);
        } else {
            // SC = exp(logits), rsum2 = row sums (no-max-sub: |logit|<~1e-3)
            gemm_fp8<EPI_EXPF32><<<gw, blk, 0, stream>>>(
                Hs, fc, SC, rsum2, nullptr, D, D, D, D, 0, 0, 0,
                a_fc[1], 0.f);
        }
    }

    normalize_1024<<<dim3(M), blk, 0, stream>>>(SC, rsum2, out);
}

// Round 8
// 344.532 us; speedup vs baseline: 1.0837x; 1.0241x over previous
//
#include <hip/hip_runtime.h>
#include <math.h>

// ---------------------------------------------------------------------------
// AttentionNet round 8: operand-swapped GEMMs (A=weights/K/VT, B=activations).
// With C = A@B^T and C/D layout col=lane&15 (token), row=(lane>>4)*4+reg
// (feature/key), each lane's 4 regs are 4 CONSECUTIVE columns of the
// row-major output -> all fp8 epilogues pack one u32 store per (i,j)
// (4x fewer store insts than round 7's byte scatter), fc2 writes aligned
// float4, rsum reduction is thread-local + 2 shuffles (was 64 shuffles).
// K-loop core untouched (r6 lesson): 16x16x128 MX-fp8 e4m3 unit-scale,
// 128x128 tile, XOR-swizzled LDS (0 conflicts), global_load_lds(16).
// 10 dispatches. Scales unchanged: x*8, W*256, L1 QKV*8, L2 QKV*1024,
// P=expS*2^-4, Hs1*256, Hs2*65536, h2*256.
// ---------------------------------------------------------------------------

typedef __attribute__((ext_vector_type(8))) int i32x8;
typedef __attribute__((ext_vector_type(4))) int i32x4;
typedef __attribute__((ext_vector_type(4))) float f32x4;
typedef unsigned char u8;
typedef unsigned int u32;

#define EPI_F8 1
#define EPI_QKV 2
#define EPI_EXP 3
#define EPI_PV 4
#define EPI_EXPF32 5

__device__ __forceinline__ void gload_lds16(const void* g, void* l) {
    __builtin_amdgcn_global_load_lds(
        (const __attribute__((address_space(1))) void*)g,
        (__attribute__((address_space(3))) void*)l, 16, 0, 0);
}

__device__ __forceinline__ u8 cvt_f8(float v) {
    return (u8)(__builtin_amdgcn_cvt_pk_fp8_f32(v, v, 0, false) & 0xFF);
}

__device__ __forceinline__ u32 pack_f8x4(float v0, float v1, float v2, float v3) {
    int p01 = __builtin_amdgcn_cvt_pk_fp8_f32(v0, v1, 0, false);
    int p23 = __builtin_amdgcn_cvt_pk_fp8_f32(v2, v3, 0, false);
    return (u32)(p01 & 0xFFFF) | ((u32)p23 << 16);
}

// C = epilogue(alpha * (A @ B^T)); A=[MA,K] fp8 (weights/K/VT side),
// B=[NB,K] fp8 (token side), batch=blockIdx.z. K % 128 == 0.
// Output is row-major [token][feature]: feature = A-row (regs = 4 consecutive),
// token = B-row (lane&15).
template <int EPI>
__global__ __launch_bounds__(256) void gemm_fp8(
    const u8* __restrict__ A, const u8* __restrict__ B,
    void* __restrict__ C0, void* __restrict__ C1, void* __restrict__ C2,
    int K, int ldA, int ldB, int ldC,
    long long bsA, long long bsB, long long bsC, float alpha, float beta)
{
    __shared__ u8 sA[128 * 128];
    __shared__ u8 sB[128 * 128];

    const int tid = threadIdx.x;
    const int wave = tid >> 6, lane = tid & 63;
    const int wm = wave >> 1, wn = wave & 1;
    const int m0 = blockIdx.y * 128, n0 = blockIdx.x * 128;
    const long long z = blockIdx.z;

    const u8* pA = A + z * bsA;
    const u8* pB = B + z * bsB;

    // Tile = 128 rows x 8 16B-chunks. LDS chunk (row,c) holds global chunk
    // c ^ (row&7). global_load_lds dst must be wave-uniform base + lane*16.
    int blkid[4], rs_[4], cs16[4];
#pragma unroll
    for (int i = 0; i < 4; i++) {
        blkid[i] = wave * 256 + i * 64 + lane;
        rs_[i] = blkid[i] >> 3;
        cs16[i] = ((blkid[i] & 7) ^ (rs_[i] & 7)) * 16;
    }

    f32x4 acc[4][4] = {};
    const int fr = lane & 15, fc2 = (lane >> 4) * 2;

    for (int k0 = 0; k0 < K; k0 += 128) {
#pragma unroll
        for (int i = 0; i < 4; i++) {
            gload_lds16(pA + (long long)(m0 + rs_[i]) * ldA + k0 + cs16[i],
                        sA + blkid[i] * 16);
            gload_lds16(pB + (long long)(n0 + rs_[i]) * ldB + k0 + cs16[i],
                        sB + blkid[i] * 16);
        }
        __syncthreads();

        i32x8 a[4], b[4];
#pragma unroll
        for (int i = 0; i < 4; i++) {
            const int row = wm * 64 + i * 16 + fr;
            const int sw = row & 7;
            i32x4 lo = *(const i32x4*)(sA + row * 128 + ((fc2 + 0) ^ sw) * 16);
            i32x4 hi = *(const i32x4*)(sA + row * 128 + ((fc2 + 1) ^ sw) * 16);
            a[i] = __builtin_shufflevector(lo, hi, 0, 1, 2, 3, 4, 5, 6, 7);
        }
#pragma unroll
        for (int j = 0; j < 4; j++) {
            const int row = wn * 64 + j * 16 + fr;
            const int sw = row & 7;
            i32x4 lo = *(const i32x4*)(sB + row * 128 + ((fc2 + 0) ^ sw) * 16);
            i32x4 hi = *(const i32x4*)(sB + row * 128 + ((fc2 + 1) ^ sw) * 16);
            b[j] = __builtin_shufflevector(lo, hi, 0, 1, 2, 3, 4, 5, 6, 7);
        }
#pragma unroll
        for (int i = 0; i < 4; i++)
#pragma unroll
            for (int j = 0; j < 4; j++)
                acc[i][j] = __builtin_amdgcn_mfma_scale_f32_16x16x128_f8f6f4(
                    a[i], b[j], acc[i][j], 0 /*A=e4m3*/, 0 /*B=e4m3*/,
                    0, 0x7F7F7F7F, 0, 0x7F7F7F7F);
        __syncthreads();
    }

    // C/D: tile row (A-dim/feature) = (lane>>4)*4 + reg, tile col (B-dim/
    // token) = lane&15.  R0 = first of 4 consecutive features; Cq = token.
    const int col = lane & 15;
    const int rbase = (lane >> 4) * 4;

    if (EPI == EPI_EXP) {
        // P[z][q][key] = fp8(exp(acc*alpha)*2^-4) packed u32 (4 keys);
        // rsum[z*2048+q] += sum exp. Thread-local partial + xor16/32 reduce.
        u8* P = (u8*)C0 + z * bsC;
        float* rsum = (float*)C1 + z * 2048;
#pragma unroll
        for (int j = 0; j < 4; j++) {
            const int Cq = n0 + wn * 64 + j * 16 + col;
            float part = 0.f;
#pragma unroll
            for (int i = 0; i < 4; i++) {
                const int R0 = m0 + wm * 64 + i * 16 + rbase;
                float e0 = __expf(acc[i][j][0] * alpha);
                float e1 = __expf(acc[i][j][1] * alpha);
                float e2 = __expf(acc[i][j][2] * alpha);
                float e3 = __expf(acc[i][j][3] * alpha);
                part += (e0 + e1) + (e2 + e3);
                *(u32*)(P + (long long)Cq * ldC + R0) =
                    pack_f8x4(e0 * 0.0625f, e1 * 0.0625f,
                              e2 * 0.0625f, e3 * 0.0625f);
            }
            part += __shfl_xor(part, 16);
            part += __shfl_xor(part, 32);
            if (lane < 16) atomicAdd(&rsum[Cq], part);
        }
        return;
    }

    if (EPI == EPI_EXPF32) {
        // E[token][class] = exp(acc*alpha) as aligned float4; rsum[token] += .
        float* Cw = (float*)C0;
        float* rsum = (float*)C1;
#pragma unroll
        for (int j = 0; j < 4; j++) {
            const int Cq = n0 + wn * 64 + j * 16 + col;
            float part = 0.f;
#pragma unroll
            for (int i = 0; i < 4; i++) {
                const int R0 = m0 + wm * 64 + i * 16 + rbase;
                float4 e;
                e.x = __expf(acc[i][j][0] * alpha);
                e.y = __expf(acc[i][j][1] * alpha);
                e.z = __expf(acc[i][j][2] * alpha);
                e.w = __expf(acc[i][j][3] * alpha);
                part += (e.x + e.y) + (e.z + e.w);
                *(float4*)(Cw + (long long)Cq * ldC + R0) = e;
            }
            part += __shfl_xor(part, 16);
            part += __shfl_xor(part, 32);
            if (lane < 16) atomicAdd(&rsum[Cq], part);
        }
        return;
    }

#pragma unroll
    for (int j = 0; j < 4; j++) {
        const int Cq = n0 + wn * 64 + j * 16 + col;
        float inv;
        if (EPI == EPI_PV) {
            const float* rsum = (const float*)C1 + z * 2048;
            inv = alpha / rsum[Cq];
        }
#pragma unroll
        for (int i = 0; i < 4; i++) {
            const int R0 = m0 + wm * 64 + i * 16 + rbase;
            if (EPI == EPI_F8) {
                u8* C = (u8*)C0 + z * bsC;
                *(u32*)(C + (long long)Cq * ldC + R0) =
                    pack_f8x4(acc[i][j][0] * alpha, acc[i][j][1] * alpha,
                              acc[i][j][2] * alpha, acc[i][j][3] * alpha);
            } else if (EPI == EPI_PV) {
                u8* C = (u8*)C0 + z * bsC;
                float v[4];
#pragma unroll
                for (int r = 0; r < 4; r++) {
                    float t = acc[i][j][r] * inv;
                    v[r] = (t / (1.f + __expf(-t))) * beta;   // silu * beta
                }
                *(u32*)(C + (long long)Cq * ldC + R0) =
                    pack_f8x4(v[0], v[1], v[2], v[3]);
            } else { // EPI_QKV: A-rows segmented 0->Q, 1->K, 2->V (V^T out)
                const int seg = R0 >> 10;       // block-uniform (m0 % 128 == 0)
                const int db = R0 & 1023;
                if (seg == 2) {
                    // V^T[bb][d][token], byte scatter over 4 d-rows
                    const int bb = Cq >> 11, tt = Cq & 2047;
                    u8* VTp = (u8*)C2;
#pragma unroll
                    for (int r = 0; r < 4; r++)
                        VTp[(long long)bb * (1024LL * 2048) +
                            (long long)(db + r) * 2048 + tt] =
                            cvt_f8(acc[i][j][r] * alpha);
                } else {
                    u8* C = seg ? (u8*)C1 : (u8*)C0;
                    *(u32*)(C + (long long)Cq * 1024 + db) =
                        pack_f8x4(acc[i][j][0] * alpha, acc[i][j][1] * alpha,
                                  acc[i][j][2] * alpha, acc[i][j][3] * alpha);
                }
            }
        }
    }
}

// One dispatch: x (8192 blocks, scale 8) + 8 weights (8192 blocks, scale 256)
// -> fp8; blocks 0..23 also zero the 3 rsum buffers (24576 floats at rz).
__global__ __launch_bounds__(256) void convert_all(
    const float* x, const float* w0, const float* w1, const float* w2,
    const float* w3, const float* w4, const float* w5, const float* w6,
    const float* w7, u8* __restrict__ ax, u8* __restrict__ wf,
    float* __restrict__ rz)
{
    const int bid = blockIdx.x;
    if (bid < 24) {
        float4 zero = {0.f, 0.f, 0.f, 0.f};
        *(float4*)(rz + ((long long)bid * 256 + threadIdx.x) * 4) = zero;
    }
    const float* src;
    u8* dst;
    float scale;
    long long i;
    if (bid < 8192) {
        src = x; dst = ax; scale = 8.f;
        i = ((long long)bid * 256 + threadIdx.x) * 4;
    } else {
        const float* ws[8] = {w0, w1, w2, w3, w4, w5, w6, w7};
        const int wi = (bid - 8192) >> 10;
        src = ws[wi]; scale = 256.f;
        dst = wf + (long long)wi * 1024 * 1024;
        i = (((long long)(bid - 8192) & 1023) * 256 + threadIdx.x) * 4;
    }
    float4 v = *(const float4*)(src + i);
    *(u32*)(dst + i) = pack_f8x4(v.x * scale, v.y * scale,
                                 v.z * scale, v.w * scale);
}

// out[row][c] = e[row][c] / rsum[row]  (1024 cols, fp32)
__global__ __launch_bounds__(256) void normalize_1024(
    const float* __restrict__ e, const float* __restrict__ rsum,
    float* __restrict__ out)
{
    const long long row = blockIdx.x;
    const float inv = 1.0f / rsum[row];
    const float* p = e + row * 1024;
    float* o = out + row * 1024;
    float4 v = *(const float4*)(p + threadIdx.x * 4);
    float4 ov;
    ov.x = v.x * inv; ov.y = v.y * inv; ov.z = v.z * inv; ov.w = v.w * inv;
    *(float4*)(o + threadIdx.x * 4) = ov;
}

extern "C" void kernel_launch(void* const* d_in, const int* in_sizes, int n_in,
                              void* d_out, int out_size, void* d_ws, size_t ws_size,
                              hipStream_t stream)
{
    float* out = (float*)d_out;

    constexpr int Bt = 4, S = 2048, D = 1024;
    constexpr int M = Bt * S;                  // 8192
    const long long MD = (long long)M * D;     // 8,388,608
    const long long DD = (long long)D * D;
    const long long SD = (long long)S * D;
    const long long SS = (long long)S * S;

    // ws layout: Af 8MB | Wf 8MB | Qf 8 | Kf 8 | VT 8 | Pf 16MB | Hs 8MB |
    // SC fp32 32MB | rsum0|rsum1|rsum2 (3 x 32KB)   => ~96 MB
    u8* Af = (u8*)d_ws;
    u8* Wf = Af + MD;
    u8* Qf = Wf + 8 * DD;
    u8* Kf = Qf + MD;
    u8* VT = Kf + MD;
    u8* Pf = VT + MD;
    u8* Hs = Pf + (long long)Bt * SS;
    float* SC = (float*)(Hs + MD);
    float* rsum0 = SC + MD;
    float* rsum1 = rsum0 + M;
    float* rsum2 = rsum1 + M;

    const dim3 blk(256);

    // per-layer alphas (exact pow2 folds; see header comment)
    const float SOFT = 0.08838834764831845f; // 1/sqrt(128)
    const float a_qkv[2] = {8.f / 2048.f, 1024.f / 65536.f};
    const float a_qk[2]  = {SOFT / 64.f, SOFT / 1048576.f};
    const float a_pv[2]  = {2.0f, 1.f / 64.f};        // then / rsum
    const float b_pv[2]  = {256.f, 65536.f};          // Hs store scale
    const float a_fc[2]  = {256.f / 65536.f, 1.f / 16777216.f};

    convert_all<<<dim3(16384), blk, 0, stream>>>(
        (const float*)d_in[0], (const float*)d_in[1], (const float*)d_in[2],
        (const float*)d_in[3], (const float*)d_in[4], (const float*)d_in[5],
        (const float*)d_in[6], (const float*)d_in[7], (const float*)d_in[8],
        Af, Wf, rsum0);

    // Swapped grids: x = token tiles (B side), y = feature/key tiles (A side)
    const dim3 gqkv(M / 128, 3 * D / 128, 1);  // (64, 24)
    const dim3 gqk(S / 128, S / 128, Bt);      // x = queries, y = keys
    const dim3 gpv(S / 128, D / 128, Bt);      // x = tokens, y = d-tiles
    const dim3 gw(M / 128, D / 128, 1);        // (64, 8)

    for (int layer = 0; layer < 2; layer++) {
        const u8* wqkv = Wf + (long long)(layer * 4) * DD; // wq|wk|wv contiguous
        const u8* fc   = Wf + (long long)(layer * 4 + 3) * DD;
        float* rsum    = layer ? rsum1 : rsum0;

        // Q/K row-major [8192,1024]; V^T [4][1024][2048]
        gemm_fp8<EPI_QKV><<<gqkv, blk, 0, stream>>>(
            wqkv, Af, Qf, Kf, VT, D, D, D, D, 0, 0, 0, a_qkv[layer], 0.f);
        // P[z][q][key] = fp8(exp(score)/16), rsum[q] = sum exp
        gemm_fp8<EPI_EXP><<<gqk, blk, 0, stream>>>(
            Kf, Qf, Pf, rsum, nullptr, D, D, D, S, SD, SD, SS,
            a_qk[layer], 0.f);
        // Hs[token][d] = fp8(silu(P@V / rsum) * b_pv)
        gemm_fp8<EPI_PV><<<gpv, blk, 0, stream>>>(
            VT, Pf, Hs, rsum, nullptr, S, S, S, D,
            (long long)D * S, SS, SD, a_pv[layer], b_pv[layer]);
        if (layer == 0) {
            gemm_fp8<EPI_F8><<<gw, blk, 0, stream>>>(
                fc, Hs, Af, nullptr, nullptr, D, D, D, D, 0, 0, 0,
                a_fc[0], 0.f);
        } else {
            // SC = exp(logits) float4, rsum2 = row sums (no-max-sub)
            gemm_fp8<EPI_EXPF32><<<gw, blk, 0, stream>>>(
                fc, Hs, SC, rsum2, nullptr, D, D, D, D, 0, 0, 0,
                a_fc[1], 0.f);
        }
    }

    normalize_1024<<<dim3(M), blk, 0, stream>>>(SC, rsum2, out);
}

// Round 9
// 336.630 us; speedup vs baseline: 1.1091x; 1.0235x over previous
//
#include <hip/hip_runtime.h>
#include <math.h>

// ---------------------------------------------------------------------------
// AttentionNet round 9: QK^T reassociation. scores = x wq^T wk x^T =
// (x@Wqk)@x^T with Wqk = wq^T wk precomputed per layer (1024x1024, batched
// z=2 GEMM from transposed fp8 weight copies). Q/K are never materialized:
// projection = [R|V] (N=2048, was N=3072) and the EXP GEMM's key operand is
// the activation buffer itself. Saves 34.4 GF of big-GEMM work for ~9 GF of
// tiny GEMMs. GEMM core untouched (r6 lesson): 16x16x128 MX-fp8 e4m3,
// 128x128 tile, XOR-swizzled LDS (0 conflicts), global_load_lds(16).
// 12 dispatches.
// Scales (pow2, exact alpha folds): x*8, w*256 (all), WqkT*1024, R1*16,
// R2*256, V1*8, V2*1024, P=expS/16, Hs1*256, Hs2*65536, h2*256.
//   R1 std ~0.41*16=6.6; R2 std ~0.018*256=4.6; WqkT std ~0.0128*1024=13 (ok)
// ---------------------------------------------------------------------------

typedef __attribute__((ext_vector_type(8))) int i32x8;
typedef __attribute__((ext_vector_type(4))) int i32x4;
typedef __attribute__((ext_vector_type(4))) float f32x4;
typedef unsigned char u8;
typedef unsigned int u32;

#define EPI_F8 1
#define EPI_RV 2
#define EPI_EXP 3
#define EPI_PV 4
#define EPI_EXPF32 5

__device__ __forceinline__ void gload_lds16(const void* g, void* l) {
    __builtin_amdgcn_global_load_lds(
        (const __attribute__((address_space(1))) void*)g,
        (__attribute__((address_space(3))) void*)l, 16, 0, 0);
}

__device__ __forceinline__ u8 cvt_f8(float v) {
    return (u8)(__builtin_amdgcn_cvt_pk_fp8_f32(v, v, 0, false) & 0xFF);
}

__device__ __forceinline__ u32 pack_f8x4(float v0, float v1, float v2, float v3) {
    int p01 = __builtin_amdgcn_cvt_pk_fp8_f32(v0, v1, 0, false);
    int p23 = __builtin_amdgcn_cvt_pk_fp8_f32(v2, v3, 0, false);
    return (u32)(p01 & 0xFFFF) | ((u32)p23 << 16);
}

// C = epilogue(alpha * (A @ B^T)); A=[MA,K] fp8 (weight/key/VT side),
// B=[NB,K] fp8 (token side), batch=blockIdx.z. K % 128 == 0.
// Output row-major [B-row][A-row]: lane's 4 regs = 4 consecutive A-rows.
template <int EPI>
__global__ __launch_bounds__(256) void gemm_fp8(
    const u8* __restrict__ A, const u8* __restrict__ B,
    void* __restrict__ C0, void* __restrict__ C1, void* __restrict__ C2,
    int K, int ldA, int ldB, int ldC,
    long long bsA, long long bsB, long long bsC, float alpha, float beta)
{
    __shared__ u8 sA[128 * 128];
    __shared__ u8 sB[128 * 128];

    const int tid = threadIdx.x;
    const int wave = tid >> 6, lane = tid & 63;
    const int wm = wave >> 1, wn = wave & 1;
    const int m0 = blockIdx.y * 128, n0 = blockIdx.x * 128;
    const long long z = blockIdx.z;

    const u8* pA = A + z * bsA;
    const u8* pB = B + z * bsB;

    // Tile = 128 rows x 8 16B-chunks. LDS chunk (row,c) holds global chunk
    // c ^ (row&7). global_load_lds dst must be wave-uniform base + lane*16.
    int blkid[4], rs_[4], cs16[4];
#pragma unroll
    for (int i = 0; i < 4; i++) {
        blkid[i] = wave * 256 + i * 64 + lane;
        rs_[i] = blkid[i] >> 3;
        cs16[i] = ((blkid[i] & 7) ^ (rs_[i] & 7)) * 16;
    }

    f32x4 acc[4][4] = {};
    const int fr = lane & 15, fc2 = (lane >> 4) * 2;

    for (int k0 = 0; k0 < K; k0 += 128) {
#pragma unroll
        for (int i = 0; i < 4; i++) {
            gload_lds16(pA + (long long)(m0 + rs_[i]) * ldA + k0 + cs16[i],
                        sA + blkid[i] * 16);
            gload_lds16(pB + (long long)(n0 + rs_[i]) * ldB + k0 + cs16[i],
                        sB + blkid[i] * 16);
        }
        __syncthreads();

        i32x8 a[4], b[4];
#pragma unroll
        for (int i = 0; i < 4; i++) {
            const int row = wm * 64 + i * 16 + fr;
            const int sw = row & 7;
            i32x4 lo = *(const i32x4*)(sA + row * 128 + ((fc2 + 0) ^ sw) * 16);
            i32x4 hi = *(const i32x4*)(sA + row * 128 + ((fc2 + 1) ^ sw) * 16);
            a[i] = __builtin_shufflevector(lo, hi, 0, 1, 2, 3, 4, 5, 6, 7);
        }
#pragma unroll
        for (int j = 0; j < 4; j++) {
            const int row = wn * 64 + j * 16 + fr;
            const int sw = row & 7;
            i32x4 lo = *(const i32x4*)(sB + row * 128 + ((fc2 + 0) ^ sw) * 16);
            i32x4 hi = *(const i32x4*)(sB + row * 128 + ((fc2 + 1) ^ sw) * 16);
            b[j] = __builtin_shufflevector(lo, hi, 0, 1, 2, 3, 4, 5, 6, 7);
        }
#pragma unroll
        for (int i = 0; i < 4; i++)
#pragma unroll
            for (int j = 0; j < 4; j++)
                acc[i][j] = __builtin_amdgcn_mfma_scale_f32_16x16x128_f8f6f4(
                    a[i], b[j], acc[i][j], 0 /*A=e4m3*/, 0 /*B=e4m3*/,
                    0, 0x7F7F7F7F, 0, 0x7F7F7F7F);
        __syncthreads();
    }

    const int col = lane & 15;       // B-row offset within 16-tile
    const int rbase = (lane >> 4) * 4; // first of 4 consecutive A-rows

    if (EPI == EPI_EXP) {
        // P[z][q][key] = fp8(exp(acc*alpha)/16) packed u32; rsum[q] += sum e
        u8* P = (u8*)C0 + z * bsC;
        float* rsum = (float*)C1 + z * 2048;
#pragma unroll
        for (int j = 0; j < 4; j++) {
            const int Cq = n0 + wn * 64 + j * 16 + col;
            float part = 0.f;
#pragma unroll
            for (int i = 0; i < 4; i++) {
                const int R0 = m0 + wm * 64 + i * 16 + rbase;
                float e0 = __expf(acc[i][j][0] * alpha);
                float e1 = __expf(acc[i][j][1] * alpha);
                float e2 = __expf(acc[i][j][2] * alpha);
                float e3 = __expf(acc[i][j][3] * alpha);
                part += (e0 + e1) + (e2 + e3);
                *(u32*)(P + (long long)Cq * ldC + R0) =
                    pack_f8x4(e0 * 0.0625f, e1 * 0.0625f,
                              e2 * 0.0625f, e3 * 0.0625f);
            }
            part += __shfl_xor(part, 16);
            part += __shfl_xor(part, 32);
            if (lane < 16) atomicAdd(&rsum[Cq], part);
        }
        return;
    }

    if (EPI == EPI_EXPF32) {
        // E[token][class] = exp(acc*alpha) float4; rsum[token] += sum
        float* Cw = (float*)C0;
        float* rsum = (float*)C1;
#pragma unroll
        for (int j = 0; j < 4; j++) {
            const int Cq = n0 + wn * 64 + j * 16 + col;
            float part = 0.f;
#pragma unroll
            for (int i = 0; i < 4; i++) {
                const int R0 = m0 + wm * 64 + i * 16 + rbase;
                float4 e;
                e.x = __expf(acc[i][j][0] * alpha);
                e.y = __expf(acc[i][j][1] * alpha);
                e.z = __expf(acc[i][j][2] * alpha);
                e.w = __expf(acc[i][j][3] * alpha);
                part += (e.x + e.y) + (e.z + e.w);
                *(float4*)(Cw + (long long)Cq * ldC + R0) = e;
            }
            part += __shfl_xor(part, 16);
            part += __shfl_xor(part, 32);
            if (lane < 16) atomicAdd(&rsum[Cq], part);
        }
        return;
    }

#pragma unroll
    for (int j = 0; j < 4; j++) {
        const int Cq = n0 + wn * 64 + j * 16 + col;
        float inv;
        if (EPI == EPI_PV) {
            const float* rsum = (const float*)C1 + z * 2048;
            inv = alpha / rsum[Cq];
        }
#pragma unroll
        for (int i = 0; i < 4; i++) {
            const int R0 = m0 + wm * 64 + i * 16 + rbase;
            if (EPI == EPI_F8) {
                u8* C = (u8*)C0 + z * bsC;
                *(u32*)(C + (long long)Cq * ldC + R0) =
                    pack_f8x4(acc[i][j][0] * alpha, acc[i][j][1] * alpha,
                              acc[i][j][2] * alpha, acc[i][j][3] * alpha);
            } else if (EPI == EPI_PV) {
                u8* C = (u8*)C0 + z * bsC;
                float v[4];
#pragma unroll
                for (int r = 0; r < 4; r++) {
                    float t = acc[i][j][r] * inv;
                    v[r] = (t / (1.f + __expf(-t))) * beta;   // silu * beta
                }
                *(u32*)(C + (long long)Cq * ldC + R0) =
                    pack_f8x4(v[0], v[1], v[2], v[3]);
            } else { // EPI_RV: A-rows 0..1023 -> R (alpha), 1024.. -> V^T (beta)
                const int seg = R0 >> 10;
                const int db = R0 & 1023;
                if (seg == 1) {
                    // V^T[bb][d][token], byte scatter over 4 d-rows
                    const int bb = Cq >> 11, tt = Cq & 2047;
                    u8* VTp = (u8*)C2;
#pragma unroll
                    for (int r = 0; r < 4; r++)
                        VTp[(long long)bb * (1024LL * 2048) +
                            (long long)(db + r) * 2048 + tt] =
                            cvt_f8(acc[i][j][r] * beta);
                } else {
                    u8* C = (u8*)C0;
                    *(u32*)(C + (long long)Cq * 1024 + db) =
                        pack_f8x4(acc[i][j][0] * alpha, acc[i][j][1] * alpha,
                                  acc[i][j][2] * alpha, acc[i][j][3] * alpha);
                }
            }
        }
    }
}

// x (8192 blocks, scale 8) + wv1|wv2|fc1|fc2 (1024 blocks each, scale 256)
// -> fp8; blocks 0..23 zero the 3 rsum buffers (24576 floats at rz).
__global__ __launch_bounds__(256) void convert_all(
    const float* x, const float* wv1, const float* wv2, const float* fc1,
    const float* fc2, u8* __restrict__ ax, u8* __restrict__ bproj,
    u8* __restrict__ wfc, float* __restrict__ rz)
{
    const int bid = blockIdx.x;
    if (bid < 24) {
        float4 zero = {0.f, 0.f, 0.f, 0.f};
        *(float4*)(rz + ((long long)bid * 256 + threadIdx.x) * 4) = zero;
    }
    const float* src;
    u8* dst;
    float scale;
    long long i;
    if (bid < 8192) {
        src = x; dst = ax; scale = 8.f;
        i = ((long long)bid * 256 + threadIdx.x) * 4;
    } else {
        const int idx = bid - 8192;
        const int wi = idx >> 10;
        const float* srcs[4] = {wv1, wv2, fc1, fc2};
        // wv1 -> Bproj[0] rows 1024+, wv2 -> Bproj[1] rows 1024+, fc -> Wfc
        u8* dsts[4] = {bproj + (1 << 20), bproj + 3 * (1 << 20),
                       wfc, wfc + (1 << 20)};
        src = srcs[wi]; dst = dsts[wi]; scale = 256.f;
        i = (((long long)(idx & 1023)) * 256 + threadIdx.x) * 4;
    }
    float4 v = *(const float4*)(src + i);
    *(u32*)(dst + i) = pack_f8x4(v.x * scale, v.y * scale,
                                 v.z * scale, v.w * scale);
}

// Transpose+convert wq1,wk1,wq2,wk2 (fp32 [1024][1024]) -> fp8^T * 256.
// Grid (256, 4); block handles a 64x64 tile; thread: 4x4 micro-tile.
__global__ __launch_bounds__(256) void convert_t(
    const float* wq1, const float* wk1, const float* wq2, const float* wk2,
    u8* __restrict__ o)
{
    const float* srcs[4] = {wq1, wk1, wq2, wk2};
    const float* src = srcs[blockIdx.y];
    u8* dst = o + (long long)blockIdx.y * (1 << 20);
    const int q0 = (blockIdx.x & 15) * 64, d0 = (blockIdx.x >> 4) * 64;
    const int qq = (threadIdx.x & 15) * 4, dd = (threadIdx.x >> 4) * 4;
    float4 v[4];
#pragma unroll
    for (int s = 0; s < 4; s++)
        v[s] = *(const float4*)(src + (long long)(q0 + qq + s) * 1024 + d0 + dd);
    const float* vf = (const float*)v;   // vf[s*4 + r]
#pragma unroll
    for (int r = 0; r < 4; r++)
        *(u32*)(dst + (long long)(d0 + dd + r) * 1024 + q0 + qq) =
            pack_f8x4(vf[0 * 4 + r] * 256.f, vf[1 * 4 + r] * 256.f,
                      vf[2 * 4 + r] * 256.f, vf[3 * 4 + r] * 256.f);
}

// out[row][c] = e[row][c] / rsum[row]  (1024 cols, fp32)
__global__ __launch_bounds__(256) void normalize_1024(
    const float* __restrict__ e, const float* __restrict__ rsum,
    float* __restrict__ out)
{
    const long long row = blockIdx.x;
    const float inv = 1.0f / rsum[row];
    const float* p = e + row * 1024;
    float* o = out + row * 1024;
    float4 v = *(const float4*)(p + threadIdx.x * 4);
    float4 ov;
    ov.x = v.x * inv; ov.y = v.y * inv; ov.z = v.z * inv; ov.w = v.w * inv;
    *(float4*)(o + threadIdx.x * 4) = ov;
}

extern "C" void kernel_launch(void* const* d_in, const int* in_sizes, int n_in,
                              void* d_out, int out_size, void* d_ws, size_t ws_size,
                              hipStream_t stream)
{
    float* out = (float*)d_out;

    constexpr int Bt = 4, S = 2048, D = 1024;
    constexpr int M = Bt * S;                  // 8192
    const long long MD = (long long)M * D;     // 8,388,608
    const long long DD = (long long)D * D;
    const long long SD = (long long)S * D;
    const long long SS = (long long)S * S;

    // ws: Af 8MB | Bproj 2x2MB | WqT 4x1MB | Wfc 2x1MB | Rf 8MB | VT 8MB |
    // Pf 16MB | Hs 8MB | SC fp32 32MB | rsum0|1|2
    u8* Af = (u8*)d_ws;
    u8* Bproj = Af + MD;                 // [2][2048][1024]: WqkT | wv
    u8* WqT = Bproj + 2 * 2048 * 1024;   // wq1T | wk1T | wq2T | wk2T
    u8* Wfc = WqT + 4 * DD;              // fc1 | fc2
    u8* Rf = Wfc + 2 * DD;
    u8* VT = Rf + MD;
    u8* Pf = VT + MD;
    u8* Hs = Pf + (long long)Bt * SS;
    float* SC = (float*)(Hs + MD);
    float* rsum0 = SC + MD;
    float* rsum1 = rsum0 + M;
    float* rsum2 = rsum1 + M;

    const dim3 blk(256);

    const float SOFT = 0.08838834764831845f; // 1/sqrt(128)
    // scale-fold alphas (all pow2 exact):
    const float a_d1   = 1.f / 64.f;               // WqkT: 256*256 -> 1024
    const float a_R[2] = {1.f / 512.f, 1.f / 1024.f};  // R1: 8*1024->16; R2: 256*1024->256
    const float b_V[2] = {1.f / 256.f, 1.f / 64.f};    // V1: 8*256->8; V2: 256*256->1024
    const float a_qk[2] = {SOFT / 128.f, SOFT / 65536.f}; // R*act scales
    const float a_pv[2] = {2.0f, 1.f / 64.f};      // 16 / V-scale, then /rsum
    const float b_pv[2] = {256.f, 65536.f};        // Hs store scale
    const float a_fc[2] = {256.f / 65536.f, 1.f / 16777216.f};

    convert_all<<<dim3(12288), blk, 0, stream>>>(
        (const float*)d_in[0], (const float*)d_in[3], (const float*)d_in[7],
        (const float*)d_in[4], (const float*)d_in[8], Af, Bproj, Wfc, rsum0);
    convert_t<<<dim3(256, 4), blk, 0, stream>>>(
        (const float*)d_in[1], (const float*)d_in[2], (const float*)d_in[5],
        (const float*)d_in[6], WqT);
    // Bproj[z] rows 0..1023 = WqkT_z = P(A=wqT_z, B=wkT_z), stored scale 1024
    gemm_fp8<EPI_F8><<<dim3(8, 8, 2), blk, 0, stream>>>(
        WqT, WqT + DD, Bproj, nullptr, nullptr, D, D, D, D,
        2 * DD, 2 * DD, (long long)2048 * 1024, a_d1, 0.f);

    const dim3 grv(M / 128, 2048 / 128, 1);    // [R|V] projection (64,16)
    const dim3 gqk(S / 128, S / 128, Bt);      // scores: x = queries, y = keys
    const dim3 gpv(S / 128, D / 128, Bt);      // x = tokens, y = d-tiles
    const dim3 gw(M / 128, D / 128, 1);        // fc GEMMs (64,8)

    for (int layer = 0; layer < 2; layer++) {
        const u8* bp = Bproj + (long long)layer * 2048 * 1024;
        const u8* fc = Wfc + (long long)layer * DD;
        float* rsum = layer ? rsum1 : rsum0;

        // R[t][j] (Rf, packed u32) and V^T[b][d][t] (VT, scatter)
        gemm_fp8<EPI_RV><<<grv, blk, 0, stream>>>(
            bp, Af, Rf, nullptr, VT, D, D, D, D, 0, 0, 0,
            a_R[layer], b_V[layer]);
        // P[z][q][key] = fp8(exp(score)/16); rsum[q] = sum exp.
        // keys side = activations themselves (Af), queries side = R.
        gemm_fp8<EPI_EXP><<<gqk, blk, 0, stream>>>(
            Af, Rf, Pf, rsum, nullptr, D, D, D, S, SD, SD, SS,
            a_qk[layer], 0.f);
        // Hs[token][d] = fp8(silu(P@V / rsum) * b_pv)
        gemm_fp8<EPI_PV><<<gpv, blk, 0, stream>>>(
            VT, Pf, Hs, rsum, nullptr, S, S, S, D,
            (long long)D * S, SS, SD, a_pv[layer], b_pv[layer]);
        if (layer == 0) {
            gemm_fp8<EPI_F8><<<gw, blk, 0, stream>>>(
                fc, Hs, Af, nullptr, nullptr, D, D, D, D, 0, 0, 0,
                a_fc[0], 0.f);
        } else {
            gemm_fp8<EPI_EXPF32><<<gw, blk, 0, stream>>>(
                fc, Hs, SC, rsum2, nullptr, D, D, D, D, 0, 0, 0,
                a_fc[1], 0.f);
        }
    }

    normalize_1024<<<dim3(M), blk, 0, stream>>>(SC, rsum2, out);
}